// Round 1
// baseline (7778.922 us; speedup 1.0000x reference)
//
#include <hip/hip_runtime.h>

typedef unsigned int u32;
typedef unsigned long long u64;

#define BN 8
#define HS 512
#define WSZ 512
#define PHS 514
#define PWS 514
#define PP (PHS*PWS)            // 264196 padded pixels / image
#define NIMG 16                 // 2 fields (pred,tgt) * 8 batch
#define NPIXP (NIMG*PP)         // 4,227,136
#define NPIMG (HS*WSZ)          // 262144
#define NPIXC (NIMG*NPIMG)      // 4,194,304
#define CAP 8192u               // hash capacity per image-field (pow2)
#define SLOT0 8192
#define NSLOT 8193
#define TOTR 66977792u          // sum of row index over 512x512 (exact)
#define TOTCC 66977792u
#define MAXL 512
#define PROP_ITERS 500

__device__ __forceinline__ u32 hashL(u32 L) { return (L * 2654435761u) >> 19; }

// monotone map double -> u64 so unsigned min == double min
__device__ __forceinline__ u64 encAng(double a) {
  u64 u = (u64)__double_as_longlong(a);
  return (u >> 63) ? ~u : (u | 0x8000000000000000ull);
}

// ---------------- init: padded label image, idx where mask else 0 -------------
__global__ __launch_bounds__(256) void k_init(const float* __restrict__ pred,
                                              const float* __restrict__ tgt,
                                              float* __restrict__ A) {
  int i = blockIdx.x * 256 + threadIdx.x;
  if (i >= NPIXP) return;
  int img = i / PP, p = i - img * PP;
  int r = p / PWS, c = p - r * PWS;
  float out = 0.f;
  if (r >= 1 && r <= HS && c >= 1 && c <= WSZ) {
    int f = img >> 3, b = img & 7;
    int q = b * NPIMG + (r - 1) * WSZ + (c - 1);
    bool m = (f == 0) ? (pred[q] > 0.f) : (tgt[q] == 1.f);
    if (m) out = (float)(b * PP + p);   // global linear idx within its own field
  }
  A[i] = out;
}

// ---------------- one masked 3x3 max-propagation step ------------------------
__global__ __launch_bounds__(256) void k_prop(const float* __restrict__ A,
                                              float* __restrict__ B) {
  int i = blockIdx.x * 256 + threadIdx.x;
  if (i >= NPIXP) return;
  int p = i % PP;
  int r = p / PWS, c = p - r * PWS;
  float v = 0.f;
  if (r >= 1 && r <= HS && c >= 1 && c <= WSZ) {
    float s = A[i];
    if (s > 0.f) {                    // masked cell <=> value > 0 (invariant)
      const float* b0 = A + i;
      float m = s;
      m = fmaxf(m, b0[-PWS - 1]); m = fmaxf(m, b0[-PWS]); m = fmaxf(m, b0[-PWS + 1]);
      m = fmaxf(m, b0[-1]);                                m = fmaxf(m, b0[1]);
      m = fmaxf(m, b0[PWS - 1]);  m = fmaxf(m, b0[PWS]);  m = fmaxf(m, b0[PWS + 1]);
      v = m;
    }
  }
  B[i] = v;
}

// ---------------- contour image: label where (mask && any 8-neighbor==0) -----
__global__ __launch_bounds__(256) void k_cimg(const float* __restrict__ A,
                                              float* __restrict__ Cm) {
  int i = blockIdx.x * 256 + threadIdx.x;   // grid exact: NPIXC/256
  int img = i / NPIMG, q = i - img * NPIMG;
  int r = (q >> 9) + 1, c = (q & 511) + 1;
  const float* b0 = A + img * PP + r * PWS + c;
  float v = b0[0];
  float out = 0.f;
  if (v > 0.f) {
    float mn = b0[-PWS - 1];
    mn = fminf(mn, b0[-PWS]); mn = fminf(mn, b0[-PWS + 1]);
    mn = fminf(mn, b0[-1]);   mn = fminf(mn, b0[1]);
    mn = fminf(mn, b0[PWS - 1]); mn = fminf(mn, b0[PWS]); mn = fminf(mn, b0[PWS + 1]);
    if (mn == 0.f) out = v;
  }
  Cm[i] = out;
}

// ---------------- pass 1: per-label count / sum_r / sum_c --------------------
__global__ __launch_bounds__(256) void k_count(const float* __restrict__ Cm,
                                               u32* __restrict__ key, u32* __restrict__ cnt,
                                               u32* __restrict__ sr, u32* __restrict__ sc) {
  __shared__ u32 s_n, s_r, s_c;
  if (threadIdx.x == 0) { s_n = 0; s_r = 0; s_c = 0; }
  __syncthreads();
  int i = blockIdx.x * 256 + threadIdx.x;
  int img = i / NPIMG, q = i - img * NPIMG;
  float v = Cm[i];
  if (v != 0.f) {
    u32 L = (u32)v;
    u32 r = (u32)(q >> 9), c = (u32)(q & 511);
    u32 h = hashL(L), slot = 0xFFFFFFFFu;
    for (u32 pr = 0; pr < CAP; ++pr) {
      u32 k = key[img * CAP + h];
      if (k == L) { slot = h; break; }
      if (k == 0u) {
        u32 old = atomicCAS(&key[img * CAP + h], 0u, L);
        if (old == 0u || old == L) { slot = h; break; }
      }
      h = (h + 1) & (CAP - 1);
    }
    if (slot != 0xFFFFFFFFu) {
      u32 s = (u32)img * NSLOT + slot;
      atomicAdd(&cnt[s], 1u); atomicAdd(&sr[s], r); atomicAdd(&sc[s], c);
    }
    atomicAdd(&s_n, 1u); atomicAdd(&s_r, r); atomicAdd(&s_c, c);  // nnz totals
  }
  __syncthreads();
  if (threadIdx.x == 0 && s_n) {
    int im = (blockIdx.x * 256) / NPIMG;          // whole block is in one image
    u32 s = (u32)im * NSLOT + SLOT0;
    atomicAdd(&cnt[s], s_n); atomicAdd(&sr[s], s_r); atomicAdd(&sc[s], s_c);
  }
}

// ---------------- pass 2: per-label min encoded angle ------------------------
__global__ __launch_bounds__(256) void k_angle(const float* __restrict__ Cm,
                                               const u32* __restrict__ key, const u32* __restrict__ cnt,
                                               const u32* __restrict__ sr, const u32* __restrict__ sc,
                                               u64* __restrict__ amin) {
  int i = blockIdx.x * 256 + threadIdx.x;
  int img = i / NPIMG, q = i - img * NPIMG;
  int r = q >> 9, c = q & 511;
  float v = Cm[i];
  bool zero = (v == 0.f);
  u64 e0 = ~0ull;
  if (zero) {
    u32 base = (u32)img * NSLOT + SLOT0;
    u32 n0 = NPIMG - cnt[base];                   // >=1 since this pixel is zero
    double cr = (double)(TOTR - sr[base]) / (double)n0;
    double cc = (double)(TOTCC - sc[base]) / (double)n0;
    e0 = encAng(atan2((double)c - cc, (double)r - cr));
  } else {
    u32 L = (u32)v;
    u32 h = hashL(L);
    for (u32 pr = 0; pr < CAP && key[img * CAP + h] != L; ++pr) h = (h + 1) & (CAP - 1);
    u32 s = (u32)img * NSLOT + h;
    u32 n = cnt[s];
    double cr = (double)sr[s] / (double)n;
    double cc = (double)sc[s] / (double)n;
    atomicMin(&amin[s], encAng(atan2((double)c - cc, (double)r - cr)));
  }
  // block-reduce the hot label-0 slot (~210k pixels/image) to 1 atomic/block
  for (int o = 32; o > 0; o >>= 1) {
    u64 other = __shfl_xor(e0, o, 64);
    e0 = other < e0 ? other : e0;
  }
  __shared__ u64 wmin[4];
  int lane = threadIdx.x & 63, wid = threadIdx.x >> 6;
  if (lane == 0) wmin[wid] = e0;
  __syncthreads();
  if (threadIdx.x == 0) {
    u64 m = wmin[0];
    for (int k = 1; k < 4; ++k) m = wmin[k] < m ? wmin[k] : m;
    if (m != ~0ull) {
      int im = (blockIdx.x * 256) / NPIMG;
      atomicMin(&amin[(u32)im * NSLOT + SLOT0], m);
    }
  }
}

// ---------------- pass 3: min row-major index among min-angle points ---------
__global__ __launch_bounds__(256) void k_idx(const float* __restrict__ Cm,
                                             const u32* __restrict__ key, const u32* __restrict__ cnt,
                                             const u32* __restrict__ sr, const u32* __restrict__ sc,
                                             const u64* __restrict__ amin, u32* __restrict__ imin) {
  int i = blockIdx.x * 256 + threadIdx.x;
  int img = i / NPIMG, q = i - img * NPIMG;
  int r = q >> 9, c = q & 511;
  float v = Cm[i];
  u32 s; double cr, cc;
  if (v == 0.f) {
    s = (u32)img * NSLOT + SLOT0;
    u32 n0 = NPIMG - cnt[s];
    cr = (double)(TOTR - sr[s]) / (double)n0;
    cc = (double)(TOTCC - sc[s]) / (double)n0;
  } else {
    u32 L = (u32)v;
    u32 h = hashL(L);
    for (u32 pr = 0; pr < CAP && key[img * CAP + h] != L; ++pr) h = (h + 1) & (CAP - 1);
    s = (u32)img * NSLOT + h;
    u32 n = cnt[s];
    cr = (double)sr[s] / (double)n;
    cc = (double)sc[s] / (double)n;
  }
  u64 e = encAng(atan2((double)c - cc, (double)r - cr));
  if (e == amin[s]) atomicMin(&imin[s], (u32)q);
}

// ---------------- gather lists, sort by label, match, reduce S ---------------
__global__ __launch_bounds__(256) void k_match(const u32* __restrict__ key,
                                               const u32* __restrict__ cnt, const u32* __restrict__ sr,
                                               const u32* __restrict__ sc, const u32* __restrict__ imin,
                                               const float* __restrict__ wp, float* __restrict__ out) {
  __shared__ u32 lbl[2][MAXL];
  __shared__ double cx[2][MAXL], cy[2][MAXL], Rr[2][MAXL];
  __shared__ int nlist[2], tot[2];
  double S = 0.0;                         // thread 0 accumulator
  for (int b = 0; b < BN; ++b) {
    __syncthreads();
    if (threadIdx.x == 0) { nlist[0] = nlist[1] = 0; tot[0] = tot[1] = 0; }
    __syncthreads();
    for (int f = 0; f < 2; ++f) {
      int t = f * BN + b;
      for (int s = threadIdx.x; s < NSLOT; s += 256) {
        u32 L, n; double ccx, ccy;
        if (s < (int)CAP) {
          L = key[t * CAP + s];
          if (L == 0u) continue;
          n = cnt[t * NSLOT + s];
          atomicAdd(&tot[f], 1);          // unique-label count (pre-MIN_PTS)
          if (n < 10u) continue;
          ccx = (double)sr[t * NSLOT + s] / (double)n;
          ccy = (double)sc[t * NSLOT + s] / (double)n;
        } else {
          u32 nn = cnt[t * NSLOT + SLOT0];
          n = NPIMG - nn;
          if (n == 0u) continue;          // label 0 absent
          atomicAdd(&tot[f], 1);
          if (n < 10u) continue;
          L = 0u;
          ccx = (double)(TOTR - sr[t * NSLOT + SLOT0]) / (double)n;
          ccy = (double)(TOTCC - sc[t * NSLOT + SLOT0]) / (double)n;
        }
        int j = atomicAdd(&nlist[f], 1);
        if (j < MAXL) {
          lbl[f][j] = L; cx[f][j] = ccx; cy[f][j] = ccy;
          u32 pi = imin[t * NSLOT + s];
          double r0 = (double)(pi >> 9), c0 = (double)(pi & 511u);
          Rr[f][j] = sqrt(r0 * r0 + c0 * c0);
        }
      }
    }
    __syncthreads();
    if (threadIdx.x == 0) {
      int np = nlist[0] > MAXL ? MAXL : nlist[0];
      int nt = nlist[1] > MAXL ? MAXL : nlist[1];
      bool vp = (tot[0] >= 2) && (np >= 1);   // labels.size>1 && len(centers)>0
      bool vt = (tot[1] >= 2) && (nt >= 1);
      if (vp && vt) {
        for (int f = 0; f < 2; ++f) {         // sort ascending by label (np.unique order)
          int n = f ? nt : np;
          for (int a = 1; a < n; ++a) {
            u32 kl = lbl[f][a]; double kx = cx[f][a], ky = cy[f][a], kr = Rr[f][a];
            int k2 = a - 1;
            while (k2 >= 0 && lbl[f][k2] > kl) {
              lbl[f][k2 + 1] = lbl[f][k2]; cx[f][k2 + 1] = cx[f][k2];
              cy[f][k2 + 1] = cy[f][k2];   Rr[f][k2 + 1] = Rr[f][k2];
              --k2;
            }
            lbl[f][k2 + 1] = kl; cx[f][k2 + 1] = kx; cy[f][k2 + 1] = ky; Rr[f][k2 + 1] = kr;
          }
        }
        double acc = 0.0;
        if (nt <= np) {
          for (int j = 0; j < nt; ++j) {
            int m = 0; double bd = 1e300;
            for (int i2 = 0; i2 < np; ++i2) {
              double dx = cx[1][j] - cx[0][i2], dy = cy[1][j] - cy[0][i2];
              double d = dx * dx + dy * dy;
              if (d < bd) { bd = d; m = i2; }
            }
            acc += fabs(Rr[0][m] - Rr[1][j]);
          }
        } else {
          for (int i2 = 0; i2 < np; ++i2) {
            int m = 0; double bd = 1e300;
            for (int j = 0; j < nt; ++j) {
              double dx = cx[0][i2] - cx[1][j], dy = cy[0][i2] - cy[1][j];
              double d = dx * dx + dy * dy;
              if (d < bd) { bd = d; m = j; }
            }
            acc += fabs(Rr[1][m] - Rr[0][i2]);
          }
        }
        S += acc * (1.5 / 3.14159265358979323846);  // sum_k 1/(k*pi), k=1,2
      }
    }
  }
  if (threadIdx.x == 0) {
    float w = wp[0];
    out[0] = (float)S * (0.5f * w * w);
  }
}

extern "C" void kernel_launch(void* const* d_in, const int* in_sizes, int n_in,
                              void* d_out, int out_size, void* d_ws, size_t ws_size,
                              hipStream_t stream) {
  const float* pred = (const float*)d_in[0];
  const float* tgt  = (const float*)d_in[1];
  const float* wp   = (const float*)d_in[2];
  float* out = (float*)d_out;

  char* ws = (char*)d_ws;
  size_t off = 0;
  float* A  = (float*)(ws + off); off += (size_t)NPIXP * 4;
  float* Bb = (float*)(ws + off); off += (size_t)NPIXP * 4;
  u32* key  = (u32*)(ws + off);   off += (size_t)NIMG * CAP * 4;
  u32* cnt  = (u32*)(ws + off);   off += (size_t)NIMG * NSLOT * 4;
  u32* sr   = (u32*)(ws + off);   off += (size_t)NIMG * NSLOT * 4;
  u32* sc   = (u32*)(ws + off);   off += (size_t)NIMG * NSLOT * 4;
  u64* amin = (u64*)(ws + off);   off += (size_t)NIMG * NSLOT * 8;
  u32* imin = (u32*)(ws + off);   off += (size_t)NIMG * NSLOT * 4;

  // zero hash tables + accumulators; 0xFF for min-trackers (contiguous regions)
  size_t zlen = (size_t)NIMG * CAP * 4 + 3ull * NIMG * NSLOT * 4;
  hipMemsetAsync(key, 0, zlen, stream);
  hipMemsetAsync(amin, 0xFF, (size_t)NIMG * NSLOT * 12, stream);

  const int gP = (NPIXP + 255) / 256;    // padded grid
  const int gC = NPIXC / 256;            // exact

  k_init<<<gP, 256, 0, stream>>>(pred, tgt, A);
  float* src = A; float* dst = Bb;
  for (int it = 0; it < PROP_ITERS; ++it) {
    k_prop<<<gP, 256, 0, stream>>>(src, dst);
    float* t2 = src; src = dst; dst = t2;
  }
  float* Cm = dst;                       // spare buffer holds compact cimg
  k_cimg<<<gC, 256, 0, stream>>>(src, Cm);
  k_count<<<gC, 256, 0, stream>>>(Cm, key, cnt, sr, sc);
  k_angle<<<gC, 256, 0, stream>>>(Cm, key, cnt, sr, sc, amin);
  k_idx<<<gC, 256, 0, stream>>>(Cm, key, cnt, sr, sc, amin, imin);
  k_match<<<1, 256, 0, stream>>>(key, cnt, sr, sc, imin, wp, out);
}

// Round 2
// 3638.707 us; speedup vs baseline: 2.1378x; 2.1378x over previous
//
#include <hip/hip_runtime.h>

typedef unsigned int u32;
typedef unsigned long long u64;

#define BN 8
#define NIMG 16                 // 2 fields (pred,tgt) * 8 batch
#define NPIMG (512*512)
#define NPIXC (NIMG*NPIMG)      // 4,194,304
#define PP (514*514)            // padded pixels per image (for label values)
#define CAP 8192u               // hash capacity per image-field (pow2)
#define SLOT0 8192
#define NSLOT 8193
#define TOTR 66977792u          // sum of row (=col) index over 512x512 (exact)
#define MAXL 512
#define PROP_ITERS 500

// ---- tiled propagation geometry ----
#define TILE 64
#define HALO 12                 // iterations per launch <= HALO
#define LROWS 90                // 1 pad + 88 data + 1 pad
#define LCF4 24                 // 1 pad + 22 data float4 + 1 pad
#define NITEMS (88*22)          // 1936 data float4 cells
#define PROPBLOCKS (NIMG*8*8)   // 1024

__device__ __forceinline__ u32 hashL(u32 L) { return (L * 2654435761u) >> 19; }

// monotone map double -> u64 so unsigned min == double min
__device__ __forceinline__ u64 encAng(double a) {
  u64 u = (u64)__double_as_longlong(a);
  return (u >> 63) ? ~u : (u | 0x8000000000000000ull);
}

// ---------------- init: compact label image ---------------------------------
__global__ __launch_bounds__(256) void k_init(const float* __restrict__ pred,
                                              const float* __restrict__ tgt,
                                              float* __restrict__ V) {
  int i = blockIdx.x * 256 + threadIdx.x;     // grid exact NPIXC/256
  int img = i >> 18, q = i & (NPIMG - 1);
  int f = img >> 3, b = img & 7;
  int r = q >> 9, c = q & 511;
  float x = (f == 0) ? pred[b * NPIMG + q] : tgt[b * NPIMG + q];
  bool m = (f == 0) ? (x > 0.f) : (x == 1.f);
  // reference label value: global linear index in the PADDED (514x514) image
  V[i] = m ? (float)(b * PP + (r + 1) * 514 + (c + 1)) : 0.f;
}

// ---------------- k iterations of masked 3x3 max, tiled in LDS --------------
__global__ __launch_bounds__(256) void k_prop(const float* __restrict__ src,
                                              float* __restrict__ dst, int niter) {
  __shared__ float4 bufA[LROWS * LCF4];   // current values
  __shared__ float4 bufB[LROWS * LCF4];   // horizontal-max scratch
  __shared__ int s_changed;
  int tid = threadIdx.x;
  int bx = blockIdx.x;
  int img = bx >> 6, t = bx & 63, ty = t >> 3, tx = t & 7;
  const float* ibase = src + img * NPIMG;

  for (int i = tid; i < LROWS * LCF4; i += 256) {
    bufA[i] = make_float4(0.f, 0.f, 0.f, 0.f);
    bufB[i] = make_float4(0.f, 0.f, 0.f, 0.f);
  }
  __syncthreads();

  float4 cur[8];
  float4 h[8];
  u32 mask = 0;
  int r0g = ty * TILE - HALO;               // global row of data row 0
  int c0g = tx * TILE - HALO;               // global col of data col 0 (mod 4 == 0)
#pragma unroll
  for (int s = 0; s < 8; ++s) {
    int it = tid + s * 256;
    float4 v = make_float4(0.f, 0.f, 0.f, 0.f);
    if (it < NITEMS) {
      int r = it / 22, dc = it - r * 22;
      int gr = r0g + r, gc = c0g + dc * 4;  // float4 is fully in or fully out
      if (gr >= 0 && gr < 512 && gc >= 0 && gc < 512)
        v = *(const float4*)(ibase + gr * 512 + gc);
      bufA[(r + 1) * LCF4 + (dc + 1)] = v;
      u32 mb = (v.x > 0.f ? 1u : 0u) | (v.y > 0.f ? 2u : 0u) |
               (v.z > 0.f ? 4u : 0u) | (v.w > 0.f ? 8u : 0u);
      mask |= mb << (s * 4);
    }
    cur[s] = v;
  }
  __syncthreads();

  for (int itr = 0; itr < niter; ++itr) {
    // phase A: horizontal 3-max (center from registers), write bufB
#pragma unroll
    for (int s = 0; s < 8; ++s) {
      int it = tid + s * 256;
      if (it < NITEMS) {
        int r = it / 22, dc = it - r * 22;
        int base = (r + 1) * LCF4 + (dc + 1);
        float4 L = bufA[base - 1], R = bufA[base + 1];
        float4 M = cur[s], hh;
        hh.x = fmaxf(L.w, fmaxf(M.x, M.y));
        hh.y = fmaxf(M.x, fmaxf(M.y, M.z));
        hh.z = fmaxf(M.y, fmaxf(M.z, M.w));
        hh.w = fmaxf(M.z, fmaxf(M.w, R.x));
        bufB[base] = hh;
        h[s] = hh;
      }
    }
    if (tid == 0) s_changed = 0;
    __syncthreads();
    // phase B: vertical 3-max of hmax (center from registers) + mask, write bufA
    bool changed = false;
#pragma unroll
    for (int s = 0; s < 8; ++s) {
      int it = tid + s * 256;
      if (it < NITEMS) {
        int r = it / 22, dc = it - r * 22;
        int base = (r + 1) * LCF4 + (dc + 1);
        float4 U = bufB[base - LCF4], D = bufB[base + LCF4];
        float4 C = h[s], v;
        v.x = fmaxf(U.x, fmaxf(C.x, D.x));
        v.y = fmaxf(U.y, fmaxf(C.y, D.y));
        v.z = fmaxf(U.z, fmaxf(C.z, D.z));
        v.w = fmaxf(U.w, fmaxf(C.w, D.w));
        u32 mb = (mask >> (s * 4)) & 15u;
        v.x = (mb & 1u) ? v.x : 0.f;
        v.y = (mb & 2u) ? v.y : 0.f;
        v.z = (mb & 4u) ? v.z : 0.f;
        v.w = (mb & 8u) ? v.w : 0.f;
        float4 o = cur[s];
        changed = changed || (v.x != o.x) || (v.y != o.y) || (v.z != o.z) || (v.w != o.w);
        cur[s] = v;
        bufA[base] = v;
      }
    }
    if (changed) s_changed = 1;
    __syncthreads();
    if (s_changed == 0) break;    // local fixpoint: remaining iters are identity
  }

  // writeback inner 64x64 (aligned float4)
  float* obase = dst + img * NPIMG;
#pragma unroll
  for (int w = 0; w < 4; ++w) {
    int wit = tid + w * 256;
    int wr = wit >> 4, wc4 = wit & 15;
    float4 v = bufA[(wr + HALO + 1) * LCF4 + (wc4 + 4)];
    *(float4*)(obase + (ty * TILE + wr) * 512 + tx * TILE + wc4 * 4) = v;
  }
}

// ---------------- contour image: label where (mask && any 8-neighbor==0) ----
__global__ __launch_bounds__(256) void k_cimg(const float* __restrict__ V,
                                              float* __restrict__ Cm) {
  int i = blockIdx.x * 256 + threadIdx.x;
  int img = i >> 18, q = i & (NPIMG - 1);
  int r = q >> 9, c = q & 511;
  const float* base = V + img * NPIMG;
  float v = base[q];
  float out = 0.f;
  if (v > 0.f) {
    bool z = (r == 0) || (r == 511) || (c == 0) || (c == 511);  // padded nbr = 0
    if (!z) {
      float mn = base[q - 513];
      mn = fminf(mn, base[q - 512]); mn = fminf(mn, base[q - 511]);
      mn = fminf(mn, base[q - 1]);   mn = fminf(mn, base[q + 1]);
      mn = fminf(mn, base[q + 511]); mn = fminf(mn, base[q + 512]);
      mn = fminf(mn, base[q + 513]);
      z = (mn == 0.f);
    }
    if (z) out = v;
  }
  Cm[i] = out;
}

// ---------------- pass 1: per-label count / sum_r / sum_c -------------------
__global__ __launch_bounds__(256) void k_count(const float* __restrict__ Cm,
                                               u32* __restrict__ key, u32* __restrict__ cnt,
                                               u32* __restrict__ sr, u32* __restrict__ sc) {
  __shared__ u32 s_n, s_r, s_c;
  if (threadIdx.x == 0) { s_n = 0; s_r = 0; s_c = 0; }
  __syncthreads();
  int i = blockIdx.x * 256 + threadIdx.x;
  int img = i >> 18, q = i & (NPIMG - 1);
  float v = Cm[i];
  if (v != 0.f) {
    u32 L = (u32)v;
    u32 r = (u32)(q >> 9), c = (u32)(q & 511);
    u32 h = hashL(L), slot = 0xFFFFFFFFu;
    for (u32 pr = 0; pr < CAP; ++pr) {
      u32 k = key[img * CAP + h];
      if (k == L) { slot = h; break; }
      if (k == 0u) {
        u32 old = atomicCAS(&key[img * CAP + h], 0u, L);
        if (old == 0u || old == L) { slot = h; break; }
      }
      h = (h + 1) & (CAP - 1);
    }
    if (slot != 0xFFFFFFFFu) {
      u32 s = (u32)img * NSLOT + slot;
      atomicAdd(&cnt[s], 1u); atomicAdd(&sr[s], r); atomicAdd(&sc[s], c);
    }
    atomicAdd(&s_n, 1u); atomicAdd(&s_r, r); atomicAdd(&s_c, c);  // nnz totals
  }
  __syncthreads();
  if (threadIdx.x == 0 && s_n) {
    int im = (blockIdx.x * 256) >> 18;            // whole block is in one image
    u32 s = (u32)im * NSLOT + SLOT0;
    atomicAdd(&cnt[s], s_n); atomicAdd(&sr[s], s_r); atomicAdd(&sc[s], s_c);
  }
}

// ---------------- pass 2: per-label min encoded angle -----------------------
__global__ __launch_bounds__(256) void k_angle(const float* __restrict__ Cm,
                                               const u32* __restrict__ key, const u32* __restrict__ cnt,
                                               const u32* __restrict__ sr, const u32* __restrict__ sc,
                                               u64* __restrict__ amin) {
  int i = blockIdx.x * 256 + threadIdx.x;
  int img = i >> 18, q = i & (NPIMG - 1);
  int r = q >> 9, c = q & 511;
  float v = Cm[i];
  u64 e0 = ~0ull;
  if (v == 0.f) {
    u32 base = (u32)img * NSLOT + SLOT0;
    u32 n0 = NPIMG - cnt[base];                   // >=1 since this pixel is zero
    double cr = (double)(TOTR - sr[base]) / (double)n0;
    double cc = (double)(TOTR - sc[base]) / (double)n0;
    e0 = encAng(atan2((double)c - cc, (double)r - cr));
  } else {
    u32 L = (u32)v;
    u32 h = hashL(L);
    for (u32 pr = 0; pr < CAP && key[img * CAP + h] != L; ++pr) h = (h + 1) & (CAP - 1);
    u32 s = (u32)img * NSLOT + h;
    u32 n = cnt[s];
    double cr = (double)sr[s] / (double)n;
    double cc = (double)sc[s] / (double)n;
    atomicMin(&amin[s], encAng(atan2((double)c - cc, (double)r - cr)));
  }
  // block-reduce the hot label-0 slot to 1 atomic/block
  for (int o = 32; o > 0; o >>= 1) {
    u64 other = __shfl_xor(e0, o, 64);
    e0 = other < e0 ? other : e0;
  }
  __shared__ u64 wmin[4];
  int lane = threadIdx.x & 63, wid = threadIdx.x >> 6;
  if (lane == 0) wmin[wid] = e0;
  __syncthreads();
  if (threadIdx.x == 0) {
    u64 m = wmin[0];
    for (int k = 1; k < 4; ++k) m = wmin[k] < m ? wmin[k] : m;
    if (m != ~0ull) {
      int im = (blockIdx.x * 256) >> 18;
      atomicMin(&amin[(u32)im * NSLOT + SLOT0], m);
    }
  }
}

// ---------------- pass 3: min row-major index among min-angle points --------
__global__ __launch_bounds__(256) void k_idx(const float* __restrict__ Cm,
                                             const u32* __restrict__ key, const u32* __restrict__ cnt,
                                             const u32* __restrict__ sr, const u32* __restrict__ sc,
                                             const u64* __restrict__ amin, u32* __restrict__ imin) {
  int i = blockIdx.x * 256 + threadIdx.x;
  int img = i >> 18, q = i & (NPIMG - 1);
  int r = q >> 9, c = q & 511;
  float v = Cm[i];
  u32 s; double cr, cc;
  if (v == 0.f) {
    s = (u32)img * NSLOT + SLOT0;
    u32 n0 = NPIMG - cnt[s];
    cr = (double)(TOTR - sr[s]) / (double)n0;
    cc = (double)(TOTR - sc[s]) / (double)n0;
  } else {
    u32 L = (u32)v;
    u32 h = hashL(L);
    for (u32 pr = 0; pr < CAP && key[img * CAP + h] != L; ++pr) h = (h + 1) & (CAP - 1);
    s = (u32)img * NSLOT + h;
    u32 n = cnt[s];
    cr = (double)sr[s] / (double)n;
    cc = (double)sc[s] / (double)n;
  }
  u64 e = encAng(atan2((double)c - cc, (double)r - cr));
  if (e == amin[s]) atomicMin(&imin[s], (u32)q);
}

// ---------------- gather lists, sort by label, match, reduce S --------------
__global__ __launch_bounds__(256) void k_match(const u32* __restrict__ key,
                                               const u32* __restrict__ cnt, const u32* __restrict__ sr,
                                               const u32* __restrict__ sc, const u32* __restrict__ imin,
                                               const float* __restrict__ wp, float* __restrict__ out) {
  __shared__ u32 lbl[2][MAXL];
  __shared__ double cx[2][MAXL], cy[2][MAXL], Rr[2][MAXL];
  __shared__ int nlist[2], tot[2];
  double S = 0.0;                         // thread 0 accumulator
  for (int b = 0; b < BN; ++b) {
    __syncthreads();
    if (threadIdx.x == 0) { nlist[0] = nlist[1] = 0; tot[0] = tot[1] = 0; }
    __syncthreads();
    for (int f = 0; f < 2; ++f) {
      int t = f * BN + b;
      for (int s = threadIdx.x; s < NSLOT; s += 256) {
        u32 L, n; double ccx, ccy;
        if (s < (int)CAP) {
          L = key[t * CAP + s];
          if (L == 0u) continue;
          n = cnt[t * NSLOT + s];
          atomicAdd(&tot[f], 1);          // unique-label count (pre-MIN_PTS)
          if (n < 10u) continue;
          ccx = (double)sr[t * NSLOT + s] / (double)n;
          ccy = (double)sc[t * NSLOT + s] / (double)n;
        } else {
          u32 nn = cnt[t * NSLOT + SLOT0];
          n = NPIMG - nn;
          if (n == 0u) continue;          // label 0 absent
          atomicAdd(&tot[f], 1);
          if (n < 10u) continue;
          L = 0u;
          ccx = (double)(TOTR - sr[t * NSLOT + SLOT0]) / (double)n;
          ccy = (double)(TOTR - sc[t * NSLOT + SLOT0]) / (double)n;
        }
        int j = atomicAdd(&nlist[f], 1);
        if (j < MAXL) {
          lbl[f][j] = L; cx[f][j] = ccx; cy[f][j] = ccy;
          u32 pi = imin[t * NSLOT + s];
          double r0 = (double)(pi >> 9), c0 = (double)(pi & 511u);
          Rr[f][j] = sqrt(r0 * r0 + c0 * c0);
        }
      }
    }
    __syncthreads();
    if (threadIdx.x == 0) {
      int np = nlist[0] > MAXL ? MAXL : nlist[0];
      int nt = nlist[1] > MAXL ? MAXL : nlist[1];
      bool vp = (tot[0] >= 2) && (np >= 1);   // labels.size>1 && len(centers)>0
      bool vt = (tot[1] >= 2) && (nt >= 1);
      if (vp && vt) {
        for (int f = 0; f < 2; ++f) {         // sort ascending by label
          int n = f ? nt : np;
          for (int a = 1; a < n; ++a) {
            u32 kl = lbl[f][a]; double kx = cx[f][a], ky = cy[f][a], kr = Rr[f][a];
            int k2 = a - 1;
            while (k2 >= 0 && lbl[f][k2] > kl) {
              lbl[f][k2 + 1] = lbl[f][k2]; cx[f][k2 + 1] = cx[f][k2];
              cy[f][k2 + 1] = cy[f][k2];   Rr[f][k2 + 1] = Rr[f][k2];
              --k2;
            }
            lbl[f][k2 + 1] = kl; cx[f][k2 + 1] = kx; cy[f][k2 + 1] = ky; Rr[f][k2 + 1] = kr;
          }
        }
        double acc = 0.0;
        if (nt <= np) {
          for (int j = 0; j < nt; ++j) {
            int m = 0; double bd = 1e300;
            for (int i2 = 0; i2 < np; ++i2) {
              double dx = cx[1][j] - cx[0][i2], dy = cy[1][j] - cy[0][i2];
              double d = dx * dx + dy * dy;
              if (d < bd) { bd = d; m = i2; }
            }
            acc += fabs(Rr[0][m] - Rr[1][j]);
          }
        } else {
          for (int i2 = 0; i2 < np; ++i2) {
            int m = 0; double bd = 1e300;
            for (int j = 0; j < nt; ++j) {
              double dx = cx[0][i2] - cx[1][j], dy = cy[0][i2] - cy[1][j];
              double d = dx * dx + dy * dy;
              if (d < bd) { bd = d; m = j; }
            }
            acc += fabs(Rr[1][m] - Rr[0][i2]);
          }
        }
        S += acc * (1.5 / 3.14159265358979323846);  // sum_k 1/(k*pi), k=1,2
      }
    }
  }
  if (threadIdx.x == 0) {
    float w = wp[0];
    out[0] = (float)S * (0.5f * w * w);
  }
}

extern "C" void kernel_launch(void* const* d_in, const int* in_sizes, int n_in,
                              void* d_out, int out_size, void* d_ws, size_t ws_size,
                              hipStream_t stream) {
  const float* pred = (const float*)d_in[0];
  const float* tgt  = (const float*)d_in[1];
  const float* wp   = (const float*)d_in[2];
  float* out = (float*)d_out;

  char* ws = (char*)d_ws;
  size_t off = 0;
  float* A  = (float*)(ws + off); off += (size_t)NPIXC * 4;
  float* Bb = (float*)(ws + off); off += (size_t)NPIXC * 4;
  u32* key  = (u32*)(ws + off);   off += (size_t)NIMG * CAP * 4;
  u32* cnt  = (u32*)(ws + off);   off += (size_t)NIMG * NSLOT * 4;
  u32* sr   = (u32*)(ws + off);   off += (size_t)NIMG * NSLOT * 4;
  u32* sc   = (u32*)(ws + off);   off += (size_t)NIMG * NSLOT * 4;
  u64* amin = (u64*)(ws + off);   off += (size_t)NIMG * NSLOT * 8;
  u32* imin = (u32*)(ws + off);   off += (size_t)NIMG * NSLOT * 4;

  size_t zlen = (size_t)NIMG * CAP * 4 + 3ull * NIMG * NSLOT * 4;
  hipMemsetAsync(key, 0, zlen, stream);
  hipMemsetAsync(amin, 0xFF, (size_t)NIMG * NSLOT * 12, stream);

  const int gC = NPIXC / 256;            // exact

  k_init<<<gC, 256, 0, stream>>>(pred, tgt, A);
  float* src = A; float* dst = Bb;
  int done = 0;
  while (done < PROP_ITERS) {
    int k = PROP_ITERS - done; if (k > HALO) k = HALO;
    k_prop<<<PROPBLOCKS, 256, 0, stream>>>(src, dst, k);
    float* t2 = src; src = dst; dst = t2;
    done += k;
  }
  float* Cm = dst;                       // spare buffer holds contour image
  k_cimg<<<gC, 256, 0, stream>>>(src, Cm);
  k_count<<<gC, 256, 0, stream>>>(Cm, key, cnt, sr, sc);
  k_angle<<<gC, 256, 0, stream>>>(Cm, key, cnt, sr, sc, amin);
  k_idx<<<gC, 256, 0, stream>>>(Cm, key, cnt, sr, sc, amin, imin);
  k_match<<<1, 256, 0, stream>>>(key, cnt, sr, sc, imin, wp, out);
}

// Round 3
// 2138.513 us; speedup vs baseline: 3.6375x; 1.7015x over previous
//
#include <hip/hip_runtime.h>

typedef unsigned int u32;
typedef unsigned long long u64;

#define BN 8
#define NIMG 16                 // 2 fields (pred,tgt) * 8 batch
#define NPIMG (512*512)
#define NPIXC (NIMG*NPIMG)      // 4,194,304
#define PP (514*514)            // padded pixels per image (for label values)
#define CAP 8192u               // hash capacity per image-field (pow2)
#define SLOT0 8192
#define NSLOT 8193
#define TOTR 66977792u          // sum of row (=col) index over 512x512 (exact)
#define MAXL 512
#define PROP_ITERS 500

// ---- tiled propagation geometry ----
#define TILE 64
#define HALO 12                 // iterations per launch <= HALO
#define EXT 88                  // 64 + 2*12 extended tile
#define CF4 22                  // EXT/4 float4 columns
#define NSTRIP 11               // 88 rows / 8 rows per thread
#define ACT (NSTRIP*CF4)        // 242 active threads
#define PROPBLOCKS (NIMG*8*8)   // 1024

__device__ __forceinline__ u32 hashL(u32 L) { return (L * 2654435761u) >> 19; }

// monotone map double -> u64 so unsigned min == double min
__device__ __forceinline__ u64 encAng(double a) {
  u64 u = (u64)__double_as_longlong(a);
  return (u >> 63) ? ~u : (u | 0x8000000000000000ull);
}

__device__ __forceinline__ float fmax3(float a, float b, float c) {
  return fmaxf(a, fmaxf(b, c));
}

// ---------------- init: compact label image ---------------------------------
__global__ __launch_bounds__(256) void k_init(const float* __restrict__ pred,
                                              const float* __restrict__ tgt,
                                              float* __restrict__ V) {
  int i = blockIdx.x * 256 + threadIdx.x;     // grid exact NPIXC/256
  int img = i >> 18, q = i & (NPIMG - 1);
  int f = img >> 3, b = img & 7;
  int r = q >> 9, c = q & 511;
  float x = (f == 0) ? pred[b * NPIMG + q] : tgt[b * NPIMG + q];
  bool m = (f == 0) ? (x > 0.f) : (x == 1.f);
  // reference label value: global linear index in the PADDED (514x514) image
  V[i] = m ? (float)(b * PP + (r + 1) * 514 + (c + 1)) : 0.f;
}

// ---------------- k iterations of masked 3x3 max, register strips -----------
// Thread (sy,tx) owns an 8-row x 1-float4 strip of the 88x88 extended tile.
// Horizontal 3-max via wave shuffles (+LDS fixup at the 3 wave-boundary lane
// pairs); vertical 3-max in registers (strip-edge rows via small LDS arrays).
__global__ __launch_bounds__(256) void k_prop(const float* __restrict__ src,
                                              float* __restrict__ dst, int niter) {
  __shared__ float4 hTop[NSTRIP][CF4];     // h row 0 of each strip
  __shared__ float4 hBot[NSTRIP][CF4];     // h row 7 of each strip
  __shared__ float fixW[3][8];             // cur.w of lanes 63,127,191
  __shared__ float fixX[3][8];             // cur.x of lanes 64,128,192
  __shared__ int s_changed;
  const int tid = threadIdx.x;
  const int bx = blockIdx.x;
  const int img = bx >> 6, tt = bx & 63, tyT = tt >> 3, txT = tt & 7;
  const float* ibase = src + img * NPIMG;
  const bool act = tid < ACT;
  const int sy = tid / CF4, tx = tid - sy * CF4;   // meaningful only if act
  const int lane = tid & 63;
  const int wIdx = tid >> 6;
  const int gr0 = tyT * TILE - HALO + sy * 8;
  const int gc = txT * TILE - HALO + tx * 4;       // float4 fully in or out

  float4 cur[8];
  u32 mask = 0;
#pragma unroll
  for (int r = 0; r < 8; ++r) {
    float4 v = make_float4(0.f, 0.f, 0.f, 0.f);
    if (act) {
      int gr = gr0 + r;
      if (gr >= 0 && gr < 512 && gc >= 0 && gc < 512)
        v = *(const float4*)(ibase + gr * 512 + gc);
    }
    cur[r] = v;
    u32 mb = (v.x > 0.f ? 1u : 0u) | (v.y > 0.f ? 2u : 0u) |
             (v.z > 0.f ? 4u : 0u) | (v.w > 0.f ? 8u : 0u);
    mask |= mb << (r * 4);
  }
  const bool wrW = act && (lane == 63);            // t = 63,127,191
  const bool wrX = act && (lane == 0) && (tid > 0);// t = 64,128,192

  for (int itr = 0; itr < niter; ++itr) {
    if (wrW) {
#pragma unroll
      for (int r = 0; r < 8; ++r) fixW[wIdx][r] = cur[r].w;
    }
    if (wrX) {
#pragma unroll
      for (int r = 0; r < 8; ++r) fixX[wIdx - 1][r] = cur[r].x;
    }
    __syncthreads();
    float4 h[8];
    if (act) {
#pragma unroll
      for (int r = 0; r < 8; ++r) {
        float4 M = cur[r];
        float Lw = __shfl_up(M.w, 1);
        float Rx = __shfl_down(M.x, 1);
        if (lane == 0 && tid > 0) Lw = fixW[wIdx - 1][r];
        if (lane == 63) Rx = fixX[wIdx][r];
        if (tx == 0) Lw = 0.f;
        if (tx == CF4 - 1) Rx = 0.f;
        float4 hh;
        hh.x = fmax3(Lw, M.x, M.y);
        hh.y = fmax3(M.x, M.y, M.z);
        hh.z = fmax3(M.y, M.z, M.w);
        hh.w = fmax3(M.z, M.w, Rx);
        h[r] = hh;
      }
      hTop[sy][tx] = h[0];
      hBot[sy][tx] = h[7];
    }
    if (tid == 0) s_changed = 0;
    __syncthreads();
    bool changed = false;
    if (act) {
      float4 above = (sy > 0) ? hBot[sy - 1][tx] : make_float4(0.f, 0.f, 0.f, 0.f);
      float4 below = (sy < NSTRIP - 1) ? hTop[sy + 1][tx] : make_float4(0.f, 0.f, 0.f, 0.f);
#pragma unroll
      for (int r = 0; r < 8; ++r) {
        float4 U = (r == 0) ? above : h[r - 1];
        float4 D = (r == 7) ? below : h[r + 1];
        float4 C = h[r], v;
        v.x = fmax3(U.x, C.x, D.x);
        v.y = fmax3(U.y, C.y, D.y);
        v.z = fmax3(U.z, C.z, D.z);
        v.w = fmax3(U.w, C.w, D.w);
        u32 mb = (mask >> (r * 4)) & 15u;
        v.x = (mb & 1u) ? v.x : 0.f;
        v.y = (mb & 2u) ? v.y : 0.f;
        v.z = (mb & 4u) ? v.z : 0.f;
        v.w = (mb & 8u) ? v.w : 0.f;
        float4 o = cur[r];
        changed = changed || (v.x != o.x) || (v.y != o.y) || (v.z != o.z) || (v.w != o.w);
        cur[r] = v;
      }
    }
    if (changed) s_changed = 1;
    __syncthreads();
    if (s_changed == 0) break;       // local fixpoint: remaining iters identity
  }

  // writeback inner 64x64 from registers (coalesced 16B stores)
  if (act && tx >= 3 && tx < 19) {
    float* obase = dst + img * NPIMG;
#pragma unroll
    for (int r = 0; r < 8; ++r) {
      int er = sy * 8 + r;
      if (er >= HALO && er < HALO + TILE)
        *(float4*)(obase + (tyT * TILE + er - HALO) * 512 + txT * TILE + (tx - 3) * 4) = cur[r];
    }
  }
}

// ---------------- contour image: label where (mask && any 8-neighbor==0) ----
__global__ __launch_bounds__(256) void k_cimg(const float* __restrict__ V,
                                              float* __restrict__ Cm) {
  int i = blockIdx.x * 256 + threadIdx.x;
  int img = i >> 18, q = i & (NPIMG - 1);
  int r = q >> 9, c = q & 511;
  const float* base = V + img * NPIMG;
  float v = base[q];
  float out = 0.f;
  if (v > 0.f) {
    bool z = (r == 0) || (r == 511) || (c == 0) || (c == 511);  // padded nbr = 0
    if (!z) {
      float mn = base[q - 513];
      mn = fminf(mn, base[q - 512]); mn = fminf(mn, base[q - 511]);
      mn = fminf(mn, base[q - 1]);   mn = fminf(mn, base[q + 1]);
      mn = fminf(mn, base[q + 511]); mn = fminf(mn, base[q + 512]);
      mn = fminf(mn, base[q + 513]);
      z = (mn == 0.f);
    }
    if (z) out = v;
  }
  Cm[i] = out;
}

// ---------------- pass 1: per-label count / sum_r / sum_c -------------------
__global__ __launch_bounds__(256) void k_count(const float* __restrict__ Cm,
                                               u32* __restrict__ key, u32* __restrict__ cnt,
                                               u32* __restrict__ sr, u32* __restrict__ sc) {
  __shared__ u32 s_n, s_r, s_c;
  if (threadIdx.x == 0) { s_n = 0; s_r = 0; s_c = 0; }
  __syncthreads();
  int i = blockIdx.x * 256 + threadIdx.x;
  int img = i >> 18, q = i & (NPIMG - 1);
  float v = Cm[i];
  if (v != 0.f) {
    u32 L = (u32)v;
    u32 r = (u32)(q >> 9), c = (u32)(q & 511);
    u32 h = hashL(L), slot = 0xFFFFFFFFu;
    for (u32 pr = 0; pr < CAP; ++pr) {
      u32 k = key[img * CAP + h];
      if (k == L) { slot = h; break; }
      if (k == 0u) {
        u32 old = atomicCAS(&key[img * CAP + h], 0u, L);
        if (old == 0u || old == L) { slot = h; break; }
      }
      h = (h + 1) & (CAP - 1);
    }
    if (slot != 0xFFFFFFFFu) {
      u32 s = (u32)img * NSLOT + slot;
      atomicAdd(&cnt[s], 1u); atomicAdd(&sr[s], r); atomicAdd(&sc[s], c);
    }
    atomicAdd(&s_n, 1u); atomicAdd(&s_r, r); atomicAdd(&s_c, c);  // nnz totals
  }
  __syncthreads();
  if (threadIdx.x == 0 && s_n) {
    int im = (blockIdx.x * 256) >> 18;            // whole block is in one image
    u32 s = (u32)im * NSLOT + SLOT0;
    atomicAdd(&cnt[s], s_n); atomicAdd(&sr[s], s_r); atomicAdd(&sc[s], s_c);
  }
}

// ---------------- pass 2: per-label min encoded angle -----------------------
__global__ __launch_bounds__(256) void k_angle(const float* __restrict__ Cm,
                                               const u32* __restrict__ key, const u32* __restrict__ cnt,
                                               const u32* __restrict__ sr, const u32* __restrict__ sc,
                                               u64* __restrict__ amin) {
  int i = blockIdx.x * 256 + threadIdx.x;
  int img = i >> 18, q = i & (NPIMG - 1);
  int r = q >> 9, c = q & 511;
  float v = Cm[i];
  u64 e0 = ~0ull;
  if (v == 0.f) {
    u32 base = (u32)img * NSLOT + SLOT0;
    u32 n0 = NPIMG - cnt[base];                   // >=1 since this pixel is zero
    double cr = (double)(TOTR - sr[base]) / (double)n0;
    double cc = (double)(TOTR - sc[base]) / (double)n0;
    e0 = encAng(atan2((double)c - cc, (double)r - cr));
  } else {
    u32 L = (u32)v;
    u32 h = hashL(L);
    for (u32 pr = 0; pr < CAP && key[img * CAP + h] != L; ++pr) h = (h + 1) & (CAP - 1);
    u32 s = (u32)img * NSLOT + h;
    u32 n = cnt[s];
    double cr = (double)sr[s] / (double)n;
    double cc = (double)sc[s] / (double)n;
    atomicMin(&amin[s], encAng(atan2((double)c - cc, (double)r - cr)));
  }
  // block-reduce the hot label-0 slot to 1 atomic/block
  for (int o = 32; o > 0; o >>= 1) {
    u64 other = __shfl_xor(e0, o, 64);
    e0 = other < e0 ? other : e0;
  }
  __shared__ u64 wmin[4];
  int lane = threadIdx.x & 63, wid = threadIdx.x >> 6;
  if (lane == 0) wmin[wid] = e0;
  __syncthreads();
  if (threadIdx.x == 0) {
    u64 m = wmin[0];
    for (int k = 1; k < 4; ++k) m = wmin[k] < m ? wmin[k] : m;
    if (m != ~0ull) {
      int im = (blockIdx.x * 256) >> 18;
      atomicMin(&amin[(u32)im * NSLOT + SLOT0], m);
    }
  }
}

// ---------------- pass 3: min row-major index among min-angle points --------
__global__ __launch_bounds__(256) void k_idx(const float* __restrict__ Cm,
                                             const u32* __restrict__ key, const u32* __restrict__ cnt,
                                             const u32* __restrict__ sr, const u32* __restrict__ sc,
                                             const u64* __restrict__ amin, u32* __restrict__ imin) {
  int i = blockIdx.x * 256 + threadIdx.x;
  int img = i >> 18, q = i & (NPIMG - 1);
  int r = q >> 9, c = q & 511;
  float v = Cm[i];
  u32 s; double cr, cc;
  if (v == 0.f) {
    s = (u32)img * NSLOT + SLOT0;
    u32 n0 = NPIMG - cnt[s];
    cr = (double)(TOTR - sr[s]) / (double)n0;
    cc = (double)(TOTR - sc[s]) / (double)n0;
  } else {
    u32 L = (u32)v;
    u32 h = hashL(L);
    for (u32 pr = 0; pr < CAP && key[img * CAP + h] != L; ++pr) h = (h + 1) & (CAP - 1);
    s = (u32)img * NSLOT + h;
    u32 n = cnt[s];
    cr = (double)sr[s] / (double)n;
    cc = (double)sc[s] / (double)n;
  }
  u64 e = encAng(atan2((double)c - cc, (double)r - cr));
  if (e == amin[s]) atomicMin(&imin[s], (u32)q);
}

// ---------------- gather lists, parallel rank-sort, parallel match ----------
__global__ __launch_bounds__(256) void k_match(const u32* __restrict__ key,
                                               const u32* __restrict__ cnt, const u32* __restrict__ sr,
                                               const u32* __restrict__ sc, const u32* __restrict__ imin,
                                               const float* __restrict__ wp, float* __restrict__ out) {
  __shared__ u32 lbl[2][MAXL];
  __shared__ double cx[2][MAXL], cy[2][MAXL], Rr[2][MAXL];
  __shared__ int nlist[2], tot[2];
  __shared__ double wsum[4];
  const int tid = threadIdx.x;
  double S = 0.0;                        // per-thread partial
  for (int b = 0; b < BN; ++b) {
    __syncthreads();
    if (tid == 0) { nlist[0] = nlist[1] = 0; tot[0] = tot[1] = 0; }
    __syncthreads();
    for (int f = 0; f < 2; ++f) {
      int t = f * BN + b;
      for (int s = tid; s < NSLOT; s += 256) {
        u32 L, n; double ccx, ccy;
        if (s < (int)CAP) {
          L = key[t * CAP + s];
          if (L == 0u) continue;
          n = cnt[t * NSLOT + s];
          atomicAdd(&tot[f], 1);          // unique-label count (pre-MIN_PTS)
          if (n < 10u) continue;
          ccx = (double)sr[t * NSLOT + s] / (double)n;
          ccy = (double)sc[t * NSLOT + s] / (double)n;
        } else {
          u32 nn = cnt[t * NSLOT + SLOT0];
          n = NPIMG - nn;
          if (n == 0u) continue;          // label 0 absent
          atomicAdd(&tot[f], 1);
          if (n < 10u) continue;
          L = 0u;
          ccx = (double)(TOTR - sr[t * NSLOT + SLOT0]) / (double)n;
          ccy = (double)(TOTR - sc[t * NSLOT + SLOT0]) / (double)n;
        }
        int j = atomicAdd(&nlist[f], 1);
        if (j < MAXL) {
          lbl[f][j] = L; cx[f][j] = ccx; cy[f][j] = ccy;
          u32 pi = imin[t * NSLOT + s];
          double r0 = (double)(pi >> 9), c0 = (double)(pi & 511u);
          Rr[f][j] = sqrt(r0 * r0 + c0 * c0);
        }
      }
    }
    __syncthreads();
    int np = nlist[0] > MAXL ? MAXL : nlist[0];
    int nt = nlist[1] > MAXL ? MAXL : nlist[1];
    bool valid = (tot[0] >= 2) && (np >= 1) && (tot[1] >= 2) && (nt >= 1);
    if (valid) {
      // parallel rank sort (labels unique -> rank is a permutation)
      u32 ml[2][2]; double mx[2][2], my[2][2], mr[2][2]; int rk[2][2]; int nh[2];
      for (int f = 0; f < 2; ++f) {
        int n = f ? nt : np;
        nh[f] = 0;
        for (int i = tid; i < n; i += 256) {
          int k = nh[f]++;
          u32 L = lbl[f][i];
          ml[f][k] = L; mx[f][k] = cx[f][i]; my[f][k] = cy[f][i]; mr[f][k] = Rr[f][i];
          int rr = 0;
          for (int j = 0; j < n; ++j) rr += (lbl[f][j] < L) ? 1 : 0;
          rk[f][k] = rr;
        }
      }
      __syncthreads();
      for (int f = 0; f < 2; ++f)
        for (int k = 0; k < nh[f]; ++k) {
          int rr = rk[f][k];
          lbl[f][rr] = ml[f][k]; cx[f][rr] = mx[f][k];
          cy[f][rr] = my[f][k];  Rr[f][rr] = mr[f][k];
        }
      __syncthreads();
      // parallel nearest-center match over rows of the smaller list
      if (nt <= np) {
        for (int j = tid; j < nt; j += 256) {
          int m = 0; double bd = 1e300;
          double tx0 = cx[1][j], ty0 = cy[1][j];
          for (int i2 = 0; i2 < np; ++i2) {
            double dx = tx0 - cx[0][i2], dy = ty0 - cy[0][i2];
            double d = dx * dx + dy * dy;
            if (d < bd) { bd = d; m = i2; }
          }
          S += fabs(Rr[0][m] - Rr[1][j]);
        }
      } else {
        for (int i2 = tid; i2 < np; i2 += 256) {
          int m = 0; double bd = 1e300;
          double px0 = cx[0][i2], py0 = cy[0][i2];
          for (int j = 0; j < nt; ++j) {
            double dx = px0 - cx[1][j], dy = py0 - cy[1][j];
            double d = dx * dx + dy * dy;
            if (d < bd) { bd = d; m = j; }
          }
          S += fabs(Rr[1][m] - Rr[0][i2]);
        }
      }
    }
  }
  // block-reduce per-thread partials
  for (int o = 32; o > 0; o >>= 1) S += __shfl_xor(S, o, 64);
  int lane = tid & 63, wid = tid >> 6;
  if (lane == 0) wsum[wid] = S;
  __syncthreads();
  if (tid == 0) {
    double total = wsum[0] + wsum[1] + wsum[2] + wsum[3];
    total *= (1.5 / 3.14159265358979323846);   // sum_k 1/(k*pi), k=1,2
    float w = wp[0];
    out[0] = (float)total * (0.5f * w * w);
  }
}

extern "C" void kernel_launch(void* const* d_in, const int* in_sizes, int n_in,
                              void* d_out, int out_size, void* d_ws, size_t ws_size,
                              hipStream_t stream) {
  const float* pred = (const float*)d_in[0];
  const float* tgt  = (const float*)d_in[1];
  const float* wp   = (const float*)d_in[2];
  float* out = (float*)d_out;

  char* ws = (char*)d_ws;
  size_t off = 0;
  float* A  = (float*)(ws + off); off += (size_t)NPIXC * 4;
  float* Bb = (float*)(ws + off); off += (size_t)NPIXC * 4;
  u32* key  = (u32*)(ws + off);   off += (size_t)NIMG * CAP * 4;
  u32* cnt  = (u32*)(ws + off);   off += (size_t)NIMG * NSLOT * 4;
  u32* sr   = (u32*)(ws + off);   off += (size_t)NIMG * NSLOT * 4;
  u32* sc   = (u32*)(ws + off);   off += (size_t)NIMG * NSLOT * 4;
  u64* amin = (u64*)(ws + off);   off += (size_t)NIMG * NSLOT * 8;
  u32* imin = (u32*)(ws + off);   off += (size_t)NIMG * NSLOT * 4;

  size_t zlen = (size_t)NIMG * CAP * 4 + 3ull * NIMG * NSLOT * 4;
  hipMemsetAsync(key, 0, zlen, stream);
  hipMemsetAsync(amin, 0xFF, (size_t)NIMG * NSLOT * 12, stream);

  const int gC = NPIXC / 256;            // exact

  k_init<<<gC, 256, 0, stream>>>(pred, tgt, A);
  float* src = A; float* dst = Bb;
  int done = 0;
  while (done < PROP_ITERS) {
    int k = PROP_ITERS - done; if (k > HALO) k = HALO;
    k_prop<<<PROPBLOCKS, 256, 0, stream>>>(src, dst, k);
    float* t2 = src; src = dst; dst = t2;
    done += k;
  }
  float* Cm = dst;                       // spare buffer holds contour image
  k_cimg<<<gC, 256, 0, stream>>>(src, Cm);
  k_count<<<gC, 256, 0, stream>>>(Cm, key, cnt, sr, sc);
  k_angle<<<gC, 256, 0, stream>>>(Cm, key, cnt, sr, sc, amin);
  k_idx<<<gC, 256, 0, stream>>>(Cm, key, cnt, sr, sc, amin, imin);
  k_match<<<1, 256, 0, stream>>>(key, cnt, sr, sc, imin, wp, out);
}

// Round 4
// 1880.159 us; speedup vs baseline: 4.1374x; 1.1374x over previous
//
#include <hip/hip_runtime.h>

typedef unsigned int u32;
typedef unsigned long long u64;

#define BN 8
#define NIMG 16                 // 2 fields (pred,tgt) * 8 batch
#define NPIMG (512*512)
#define NPIXC (NIMG*NPIMG)      // 4,194,304
#define PP (514*514)            // padded pixels per image (for label values)
#define CAP 8192u               // hash capacity per image-field (pow2)
#define SLOT0 8192
#define NSLOT 8193
#define NDN (NIMG*NSLOT)
#define TOTR 66977792u          // sum of row (=col) index over 512x512 (exact)
#define MAXL 512
#define PROP_ITERS 500

// ---- tiled propagation geometry ----
#define TILE 64
#define HALO 12                 // iterations per launch <= HALO
#define EXT 88                  // 64 + 2*12 extended tile
#define CF4 22                  // EXT/4 float4 columns
#define NSTRIP 11               // 88 rows / 8 rows per thread
#define ACT (NSTRIP*CF4)        // 242 active threads
#define PROPBLOCKS (NIMG*8*8)   // 1024

__device__ __forceinline__ u32 hashL(u32 L) { return (L * 2654435761u) >> 19; }

// monotone map double -> u64 so unsigned min == double min
__device__ __forceinline__ u64 encAng(double a) {
  u64 u = (u64)__double_as_longlong(a);
  return (u >> 63) ? ~u : (u | 0x8000000000000000ull);
}

__device__ __forceinline__ float fmax3(float a, float b, float c) {
  return fmaxf(a, fmaxf(b, c));
}

// ---------------- init: compact label image ---------------------------------
__global__ __launch_bounds__(256) void k_init(const float* __restrict__ pred,
                                              const float* __restrict__ tgt,
                                              float* __restrict__ V) {
  int i = blockIdx.x * 256 + threadIdx.x;     // grid exact NPIXC/256
  int img = i >> 18, q = i & (NPIMG - 1);
  int f = img >> 3, b = img & 7;
  int r = q >> 9, c = q & 511;
  float x = (f == 0) ? pred[b * NPIMG + q] : tgt[b * NPIMG + q];
  bool m = (f == 0) ? (x > 0.f) : (x == 1.f);
  // reference label value: global linear index in the PADDED (514x514) image
  V[i] = m ? (float)(b * PP + (r + 1) * 514 + (c + 1)) : 0.f;
}

// ---------------- k iterations of masked 3x3 max, register strips -----------
__global__ __launch_bounds__(256) void k_prop(const float* __restrict__ src,
                                              float* __restrict__ dst, int niter) {
  __shared__ float4 hTop[NSTRIP][CF4];     // h row 0 of each strip
  __shared__ float4 hBot[NSTRIP][CF4];     // h row 7 of each strip
  __shared__ float fixW[3][8];             // cur.w of lanes 63,127,191
  __shared__ float fixX[3][8];             // cur.x of lanes 64,128,192
  __shared__ int s_changed;
  const int tid = threadIdx.x;
  const int bx = blockIdx.x;
  const int img = bx >> 6, tt = bx & 63, tyT = tt >> 3, txT = tt & 7;
  const float* ibase = src + img * NPIMG;
  const bool act = tid < ACT;
  const int sy = tid / CF4, tx = tid - sy * CF4;   // meaningful only if act
  const int lane = tid & 63;
  const int wIdx = tid >> 6;
  const int gr0 = tyT * TILE - HALO + sy * 8;
  const int gc = txT * TILE - HALO + tx * 4;       // float4 fully in or out

  float4 cur[8];
  u32 mask = 0;
#pragma unroll
  for (int r = 0; r < 8; ++r) {
    float4 v = make_float4(0.f, 0.f, 0.f, 0.f);
    if (act) {
      int gr = gr0 + r;
      if (gr >= 0 && gr < 512 && gc >= 0 && gc < 512)
        v = *(const float4*)(ibase + gr * 512 + gc);
    }
    cur[r] = v;
    u32 mb = (v.x > 0.f ? 1u : 0u) | (v.y > 0.f ? 2u : 0u) |
             (v.z > 0.f ? 4u : 0u) | (v.w > 0.f ? 8u : 0u);
    mask |= mb << (r * 4);
  }
  const bool wrW = act && (lane == 63);            // t = 63,127,191
  const bool wrX = act && (lane == 0) && (tid > 0);// t = 64,128,192

  for (int itr = 0; itr < niter; ++itr) {
    if (wrW) {
#pragma unroll
      for (int r = 0; r < 8; ++r) fixW[wIdx][r] = cur[r].w;
    }
    if (wrX) {
#pragma unroll
      for (int r = 0; r < 8; ++r) fixX[wIdx - 1][r] = cur[r].x;
    }
    __syncthreads();
    float4 h[8];
    if (act) {
#pragma unroll
      for (int r = 0; r < 8; ++r) {
        float4 M = cur[r];
        float Lw = __shfl_up(M.w, 1);
        float Rx = __shfl_down(M.x, 1);
        if (lane == 0 && tid > 0) Lw = fixW[wIdx - 1][r];
        if (lane == 63) Rx = fixX[wIdx][r];
        if (tx == 0) Lw = 0.f;
        if (tx == CF4 - 1) Rx = 0.f;
        float4 hh;
        hh.x = fmax3(Lw, M.x, M.y);
        hh.y = fmax3(M.x, M.y, M.z);
        hh.z = fmax3(M.y, M.z, M.w);
        hh.w = fmax3(M.z, M.w, Rx);
        h[r] = hh;
      }
      hTop[sy][tx] = h[0];
      hBot[sy][tx] = h[7];
    }
    if (tid == 0) s_changed = 0;
    __syncthreads();
    bool changed = false;
    if (act) {
      float4 above = (sy > 0) ? hBot[sy - 1][tx] : make_float4(0.f, 0.f, 0.f, 0.f);
      float4 below = (sy < NSTRIP - 1) ? hTop[sy + 1][tx] : make_float4(0.f, 0.f, 0.f, 0.f);
#pragma unroll
      for (int r = 0; r < 8; ++r) {
        float4 U = (r == 0) ? above : h[r - 1];
        float4 D = (r == 7) ? below : h[r + 1];
        float4 C = h[r], v;
        v.x = fmax3(U.x, C.x, D.x);
        v.y = fmax3(U.y, C.y, D.y);
        v.z = fmax3(U.z, C.z, D.z);
        v.w = fmax3(U.w, C.w, D.w);
        u32 mb = (mask >> (r * 4)) & 15u;
        v.x = (mb & 1u) ? v.x : 0.f;
        v.y = (mb & 2u) ? v.y : 0.f;
        v.z = (mb & 4u) ? v.z : 0.f;
        v.w = (mb & 8u) ? v.w : 0.f;
        float4 o = cur[r];
        changed = changed || (v.x != o.x) || (v.y != o.y) || (v.z != o.z) || (v.w != o.w);
        cur[r] = v;
      }
    }
    if (changed) s_changed = 1;
    __syncthreads();
    if (s_changed == 0) break;       // local fixpoint: remaining iters identity
  }

  // writeback inner 64x64 from registers (coalesced 16B stores)
  if (act && tx >= 3 && tx < 19) {
    float* obase = dst + img * NPIMG;
#pragma unroll
    for (int r = 0; r < 8; ++r) {
      int er = sy * 8 + r;
      if (er >= HALO && er < HALO + TILE)
        *(float4*)(obase + (tyT * TILE + er - HALO) * 512 + txT * TILE + (tx - 3) * 4) = cur[r];
    }
  }
}

// ------- fused: contour image + per-label count / sum_r / sum_c -------------
__global__ __launch_bounds__(256) void k_cimgcount(const float* __restrict__ V,
                                                   float* __restrict__ Cm,
                                                   u32* __restrict__ key, u32* __restrict__ cnt,
                                                   u32* __restrict__ sr, u32* __restrict__ sc) {
  __shared__ u32 s_n, s_r, s_c;
  if (threadIdx.x == 0) { s_n = 0; s_r = 0; s_c = 0; }
  __syncthreads();
  int i = blockIdx.x * 256 + threadIdx.x;
  int img = i >> 18, q = i & (NPIMG - 1);
  int r = q >> 9, c = q & 511;
  const float* base = V + img * NPIMG;
  float v = base[q];
  float out = 0.f;
  if (v > 0.f) {
    bool z = (r == 0) || (r == 511) || (c == 0) || (c == 511);  // padded nbr = 0
    if (!z) {
      float mn = base[q - 513];
      mn = fminf(mn, base[q - 512]); mn = fminf(mn, base[q - 511]);
      mn = fminf(mn, base[q - 1]);   mn = fminf(mn, base[q + 1]);
      mn = fminf(mn, base[q + 511]); mn = fminf(mn, base[q + 512]);
      mn = fminf(mn, base[q + 513]);
      z = (mn == 0.f);
    }
    if (z) out = v;
  }
  Cm[i] = out;
  if (out != 0.f) {
    u32 L = (u32)out;
    u32 h = hashL(L), slot = 0xFFFFFFFFu;
    for (u32 pr = 0; pr < CAP; ++pr) {
      u32 k = key[img * CAP + h];
      if (k == L) { slot = h; break; }
      if (k == 0u) {
        u32 old = atomicCAS(&key[img * CAP + h], 0u, L);
        if (old == 0u || old == L) { slot = h; break; }
      }
      h = (h + 1) & (CAP - 1);
    }
    if (slot != 0xFFFFFFFFu) {
      u32 s = (u32)img * NSLOT + slot;
      atomicAdd(&cnt[s], 1u); atomicAdd(&sr[s], (u32)r); atomicAdd(&sc[s], (u32)c);
    }
    atomicAdd(&s_n, 1u); atomicAdd(&s_r, (u32)r); atomicAdd(&s_c, (u32)c);
  }
  __syncthreads();
  if (threadIdx.x == 0 && s_n) {
    int im = (blockIdx.x * 256) >> 18;            // whole block is in one image
    u32 s = (u32)im * NSLOT + SLOT0;
    atomicAdd(&cnt[s], s_n); atomicAdd(&sr[s], s_r); atomicAdd(&sc[s], s_c);
  }
}

// ------- compact occupied hash slots (+label 0) into dense per-image lists --
__global__ __launch_bounds__(256) void k_compact(const u32* __restrict__ key,
                                                 const u32* __restrict__ cnt,
                                                 const u32* __restrict__ sr, const u32* __restrict__ sc,
                                                 u32* __restrict__ nlab, u32* __restrict__ labD,
                                                 u32* __restrict__ cntD, u32* __restrict__ srD,
                                                 u32* __restrict__ scD, u32* __restrict__ slotD) {
  int i = blockIdx.x * 256 + threadIdx.x;
  if (i >= NDN) return;
  int img = i / NSLOT, s = i - img * NSLOT;
  u32 L, n, a, b2;
  if (s < (int)CAP) {
    L = key[img * CAP + s];
    if (L == 0u) return;
    n = cnt[img * NSLOT + s];
    a = sr[img * NSLOT + s]; b2 = sc[img * NSLOT + s];
  } else {
    u32 nn = cnt[img * NSLOT + SLOT0];
    n = NPIMG - nn;                     // label-0 (background) pixel count
    if (n == 0u) return;
    L = 0u;
    a = TOTR - sr[img * NSLOT + SLOT0]; b2 = TOTR - sc[img * NSLOT + SLOT0];
  }
  u32 j = atomicAdd(&nlab[img], 1u);
  if (j < MAXL) {
    labD[img * MAXL + j] = L; cntD[img * MAXL + j] = n;
    srD[img * MAXL + j] = a;  scD[img * MAXL + j] = b2;
    slotD[img * MAXL + j] = (u32)s;
  }
}

// ---------------- pass 2: per-label min encoded angle -----------------------
__global__ __launch_bounds__(256) void k_angle(const float* __restrict__ Cm,
                                               const u32* __restrict__ key, const u32* __restrict__ cnt,
                                               const u32* __restrict__ sr, const u32* __restrict__ sc,
                                               u64* __restrict__ amin) {
  int i = blockIdx.x * 256 + threadIdx.x;
  int img = i >> 18, q = i & (NPIMG - 1);
  int r = q >> 9, c = q & 511;
  float v = Cm[i];
  u64 e0 = ~0ull;
  if (v == 0.f) {
    u32 base = (u32)img * NSLOT + SLOT0;
    u32 n0 = NPIMG - cnt[base];                   // >=1 since this pixel is zero
    double cr = (double)(TOTR - sr[base]) / (double)n0;
    double cc = (double)(TOTR - sc[base]) / (double)n0;
    e0 = encAng(atan2((double)c - cc, (double)r - cr));
  } else {
    u32 L = (u32)v;
    u32 h = hashL(L);
    for (u32 pr = 0; pr < CAP && key[img * CAP + h] != L; ++pr) h = (h + 1) & (CAP - 1);
    u32 s = (u32)img * NSLOT + h;
    u32 n = cnt[s];
    double cr = (double)sr[s] / (double)n;
    double cc = (double)sc[s] / (double)n;
    atomicMin(&amin[s], encAng(atan2((double)c - cc, (double)r - cr)));
  }
  // block-reduce the hot label-0 slot to 1 atomic/block
  for (int o = 32; o > 0; o >>= 1) {
    u64 other = __shfl_xor(e0, o, 64);
    e0 = other < e0 ? other : e0;
  }
  __shared__ u64 wmin[4];
  int lane = threadIdx.x & 63, wid = threadIdx.x >> 6;
  if (lane == 0) wmin[wid] = e0;
  __syncthreads();
  if (threadIdx.x == 0) {
    u64 m = wmin[0];
    for (int k = 1; k < 4; ++k) m = wmin[k] < m ? wmin[k] : m;
    if (m != ~0ull) {
      int im = (blockIdx.x * 256) >> 18;
      atomicMin(&amin[(u32)im * NSLOT + SLOT0], m);
    }
  }
}

// ---------------- pass 3: min row-major index among min-angle points --------
__global__ __launch_bounds__(256) void k_idx(const float* __restrict__ Cm,
                                             const u32* __restrict__ key, const u32* __restrict__ cnt,
                                             const u32* __restrict__ sr, const u32* __restrict__ sc,
                                             const u64* __restrict__ amin, u32* __restrict__ imin) {
  int i = blockIdx.x * 256 + threadIdx.x;
  int img = i >> 18, q = i & (NPIMG - 1);
  int r = q >> 9, c = q & 511;
  float v = Cm[i];
  u32 s; double cr, cc;
  if (v == 0.f) {
    s = (u32)img * NSLOT + SLOT0;
    u32 n0 = NPIMG - cnt[s];
    cr = (double)(TOTR - sr[s]) / (double)n0;
    cc = (double)(TOTR - sc[s]) / (double)n0;
  } else {
    u32 L = (u32)v;
    u32 h = hashL(L);
    for (u32 pr = 0; pr < CAP && key[img * CAP + h] != L; ++pr) h = (h + 1) & (CAP - 1);
    s = (u32)img * NSLOT + h;
    u32 n = cnt[s];
    cr = (double)sr[s] / (double)n;
    cc = (double)sc[s] / (double)n;
  }
  u64 e = encAng(atan2((double)c - cc, (double)r - cr));
  if (e == amin[s]) atomicMin(&imin[s], (u32)q);
}

// ------- gather dense lists, parallel rank-sort, parallel match -------------
__global__ __launch_bounds__(256) void k_match(const u32* __restrict__ nlab,
                                               const u32* __restrict__ labD, const u32* __restrict__ cntD,
                                               const u32* __restrict__ srD, const u32* __restrict__ scD,
                                               const u32* __restrict__ slotD, const u32* __restrict__ imin,
                                               const float* __restrict__ wp, float* __restrict__ out) {
  __shared__ u32 lbl[2][MAXL];
  __shared__ double cx[2][MAXL], cy[2][MAXL], Rr[2][MAXL];
  __shared__ int nlist[2];
  __shared__ double wsum[4];
  const int tid = threadIdx.x;
  double S = 0.0;                        // per-thread partial
  for (int b = 0; b < BN; ++b) {
    __syncthreads();
    if (tid == 0) { nlist[0] = nlist[1] = 0; }
    __syncthreads();
    int tot[2];
    for (int f = 0; f < 2; ++f) {
      int t = f * BN + b;
      int ntot = (int)nlab[t];
      tot[f] = ntot;                     // unique-label count (pre-MIN_PTS)
      int nl = ntot > MAXL ? MAXL : ntot;
      for (int s2 = tid; s2 < nl; s2 += 256) {
        u32 n = cntD[t * MAXL + s2];
        if (n < 10u) continue;
        int j = atomicAdd(&nlist[f], 1); // j < MAXL guaranteed
        lbl[f][j] = labD[t * MAXL + s2];
        cx[f][j] = (double)srD[t * MAXL + s2] / (double)n;
        cy[f][j] = (double)scD[t * MAXL + s2] / (double)n;
        u32 pi = imin[t * NSLOT + slotD[t * MAXL + s2]];
        double r0 = (double)(pi >> 9), c0 = (double)(pi & 511u);
        Rr[f][j] = sqrt(r0 * r0 + c0 * c0);
      }
    }
    __syncthreads();
    int np = nlist[0], nt = nlist[1];
    bool valid = (tot[0] >= 2) && (np >= 1) && (tot[1] >= 2) && (nt >= 1);
    if (valid) {
      // parallel rank sort (labels unique -> rank is a permutation)
      u32 ml[2][2]; double mx[2][2], my[2][2], mr[2][2]; int rk[2][2]; int nh[2];
      for (int f = 0; f < 2; ++f) {
        int n = f ? nt : np;
        nh[f] = 0;
        for (int i = tid; i < n; i += 256) {
          int k = nh[f]++;
          u32 L = lbl[f][i];
          ml[f][k] = L; mx[f][k] = cx[f][i]; my[f][k] = cy[f][i]; mr[f][k] = Rr[f][i];
          int rr = 0;
          for (int j = 0; j < n; ++j) rr += (lbl[f][j] < L) ? 1 : 0;
          rk[f][k] = rr;
        }
      }
      __syncthreads();
      for (int f = 0; f < 2; ++f)
        for (int k = 0; k < nh[f]; ++k) {
          int rr = rk[f][k];
          lbl[f][rr] = ml[f][k]; cx[f][rr] = mx[f][k];
          cy[f][rr] = my[f][k];  Rr[f][rr] = mr[f][k];
        }
      __syncthreads();
      // parallel nearest-center match over rows of the smaller list
      if (nt <= np) {
        for (int j = tid; j < nt; j += 256) {
          int m = 0; double bd = 1e300;
          double tx0 = cx[1][j], ty0 = cy[1][j];
          for (int i2 = 0; i2 < np; ++i2) {
            double dx = tx0 - cx[0][i2], dy = ty0 - cy[0][i2];
            double d = dx * dx + dy * dy;
            if (d < bd) { bd = d; m = i2; }
          }
          S += fabs(Rr[0][m] - Rr[1][j]);
        }
      } else {
        for (int i2 = tid; i2 < np; i2 += 256) {
          int m = 0; double bd = 1e300;
          double px0 = cx[0][i2], py0 = cy[0][i2];
          for (int j = 0; j < nt; ++j) {
            double dx = px0 - cx[1][j], dy = py0 - cy[1][j];
            double d = dx * dx + dy * dy;
            if (d < bd) { bd = d; m = j; }
          }
          S += fabs(Rr[1][m] - Rr[0][i2]);
        }
      }
    }
  }
  // block-reduce per-thread partials
  for (int o = 32; o > 0; o >>= 1) S += __shfl_xor(S, o, 64);
  int lane = tid & 63, wid = tid >> 6;
  if (lane == 0) wsum[wid] = S;
  __syncthreads();
  if (tid == 0) {
    double total = wsum[0] + wsum[1] + wsum[2] + wsum[3];
    total *= (1.5 / 3.14159265358979323846);   // sum_k 1/(k*pi), k=1,2
    float w = wp[0];
    out[0] = (float)total * (0.5f * w * w);
  }
}

extern "C" void kernel_launch(void* const* d_in, const int* in_sizes, int n_in,
                              void* d_out, int out_size, void* d_ws, size_t ws_size,
                              hipStream_t stream) {
  const float* pred = (const float*)d_in[0];
  const float* tgt  = (const float*)d_in[1];
  const float* wp   = (const float*)d_in[2];
  float* out = (float*)d_out;

  char* ws = (char*)d_ws;
  size_t off = 0;
  float* A  = (float*)(ws + off); off += (size_t)NPIXC * 4;
  float* Bb = (float*)(ws + off); off += (size_t)NPIXC * 4;
  u32* key  = (u32*)(ws + off);   off += (size_t)NIMG * CAP * 4;
  u32* cnt  = (u32*)(ws + off);   off += (size_t)NIMG * NSLOT * 4;
  u32* sr   = (u32*)(ws + off);   off += (size_t)NIMG * NSLOT * 4;
  u32* sc   = (u32*)(ws + off);   off += (size_t)NIMG * NSLOT * 4;
  u64* amin = (u64*)(ws + off);   off += (size_t)NIMG * NSLOT * 8;
  u32* imin = (u32*)(ws + off);   off += (size_t)NIMG * NSLOT * 4;
  u32* nlab = (u32*)(ws + off);   off += (size_t)NIMG * 4;
  u32* labD = (u32*)(ws + off);   off += (size_t)NIMG * MAXL * 4;
  u32* cntD = (u32*)(ws + off);   off += (size_t)NIMG * MAXL * 4;
  u32* srD  = (u32*)(ws + off);   off += (size_t)NIMG * MAXL * 4;
  u32* scD  = (u32*)(ws + off);   off += (size_t)NIMG * MAXL * 4;
  u32* slotD= (u32*)(ws + off);   off += (size_t)NIMG * MAXL * 4;

  size_t zlen = (size_t)NIMG * CAP * 4 + 3ull * NIMG * NSLOT * 4;
  hipMemsetAsync(key, 0, zlen, stream);
  hipMemsetAsync(amin, 0xFF, (size_t)NIMG * NSLOT * 12, stream);
  hipMemsetAsync(nlab, 0, (size_t)NIMG * 4, stream);

  const int gC = NPIXC / 256;            // exact
  const int gS = (NDN + 255) / 256;      // slot-compaction grid

  k_init<<<gC, 256, 0, stream>>>(pred, tgt, A);
  float* src = A; float* dst = Bb;
  int done = 0;
  while (done < PROP_ITERS) {
    int k = PROP_ITERS - done; if (k > HALO) k = HALO;
    k_prop<<<PROPBLOCKS, 256, 0, stream>>>(src, dst, k);
    float* t2 = src; src = dst; dst = t2;
    done += k;
  }
  float* Cm = dst;                       // spare buffer holds contour image
  k_cimgcount<<<gC, 256, 0, stream>>>(src, Cm, key, cnt, sr, sc);
  k_compact<<<gS, 256, 0, stream>>>(key, cnt, sr, sc, nlab, labD, cntD, srD, scD, slotD);
  k_angle<<<gC, 256, 0, stream>>>(Cm, key, cnt, sr, sc, amin);
  k_idx<<<gC, 256, 0, stream>>>(Cm, key, cnt, sr, sc, amin, imin);
  k_match<<<1, 256, 0, stream>>>(nlab, labD, cntD, srD, scD, slotD, imin, wp, out);
}